// Round 10
// baseline (130.687 us; speedup 1.0000x reference)
//
#include <hip/hip_runtime.h>
#include <hip/hip_bf16.h>

typedef __attribute__((ext_vector_type(8))) short short8;
typedef __attribute__((ext_vector_type(16))) float f32x16;

#define B_N 4
#define SEQ 2048
#define NH 16
#define HDIM 128
#define QT 256      // q rows per block (8 waves x 32)
#define QW 32       // q rows per wave
#define KT 64       // k tile
#define NT (SEQ / KT)            // 32 tiles
#define TILE_BYTES 32768         // 16KB K frags + 16KB V frags
#define WS_NEEDED ((size_t)B_N * NH * NT * TILE_BYTES)   // 67,108,864 B

static __device__ __forceinline__ unsigned short f2bf(float f) {
  union { __hip_bfloat16 h; unsigned short u; } cv;
  cv.h = __float2bfloat16(f);
  return cv.u;
}
static __device__ __forceinline__ unsigned int pack2(float a, float b) {
  return (unsigned int)f2bf(a) | ((unsigned int)f2bf(b) << 16);
}
static __device__ __forceinline__ unsigned int cvtpk(float lo, float hi) {
  unsigned int r;
  asm("v_cvt_pk_bf16_f32 %0, %1, %2" : "=v"(r) : "v"(lo), "v"(hi));
  return r;
}
// raw v_exp_f32 (log2-domain exp); OCML exp2f adds range-fixup VALU we don't need.
static __device__ __forceinline__ float rexp2(float x) {
  return __builtin_amdgcn_exp2f(x);
}
static __device__ __forceinline__ void gload16(const void* g, void* l) {
  __builtin_amdgcn_global_load_lds(
      (const __attribute__((address_space(1))) unsigned int*)g,
      (__attribute__((address_space(3))) unsigned int*)l, 16, 0, 0);
}

// ============ pre-pass: K,V fp32 -> bf16 fragment-major tiles in ws ============
// Tile image (32 KB): [16 K-frags][16 V-frags], each frag 1 KB = 64 lanes x 16B.
__global__ __launch_bounds__(256)
void prepass(const float* __restrict__ Kg, const float* __restrict__ Vg,
             char* __restrict__ ws)
{
  __shared__ __align__(16) char tile[16384];
  const int t  = blockIdx.x;        // 0..NT-1
  const int bh = blockIdx.y;        // 0..63
  const int b  = bh >> 4, hh = bh & (NH - 1);
  const int tid = threadIdx.x;
  const long strideS = (long)NH * HDIM;
  const float* kb = Kg + ((long)b * SEQ + t * KT) * strideS + (long)hh * HDIM;
  const float* vb = Vg + ((long)b * SEQ + t * KT) * strideS + (long)hh * HDIM;
  char* out = ws + ((long)bh * NT + t) * TILE_BYTES;

  // ---- K half ----
#pragma unroll
  for (int i = 0; i < 8; ++i) {
    int f4 = tid + i * 256;            // 0..2047
    int row = f4 >> 5, c4 = f4 & 31;   // row 0..63, float4-col 0..31
    float4 x = *(const float4*)(kb + (long)row * strideS + c4 * 4);
    uint2 w; w.x = pack2(x.x, x.y); w.y = pack2(x.z, x.w);
    int f    = (row >> 5) * 8 + (c4 >> 2);
    int lane = (((c4 >> 1) & 1) << 5) | (row & 31);
    *(uint2*)(tile + f * 1024 + lane * 16 + (c4 & 1) * 8) = w;
  }
  __syncthreads();
#pragma unroll
  for (int i = 0; i < 4; ++i)
    *(uint4*)(out + tid * 16 + i * 4096) = *(const uint4*)(tile + tid * 16 + i * 4096);
  __syncthreads();

  // ---- V half (transpose via 4x4 blocks) ----
#pragma unroll
  for (int i = 0; i < 2; ++i) {
    int blk = tid + i * 256;           // 0..511
    int d4 = blk & 31, k4 = blk >> 5;  // d-block 0..31, k-block 0..15
    const float* vp = vb + (long)(k4 * 4) * strideS + d4 * 4;
    float4 r0 = *(const float4*)vp;
    float4 r1 = *(const float4*)(vp + strideS);
    float4 r2 = *(const float4*)(vp + 2 * strideS);
    float4 r3 = *(const float4*)(vp + 3 * strideS);
    const float c0[4] = {r0.x, r0.y, r0.z, r0.w};
    const float c1[4] = {r1.x, r1.y, r1.z, r1.w};
    const float c2[4] = {r2.x, r2.y, r2.z, r2.w};
    const float c3[4] = {r3.x, r3.y, r3.z, r3.w};
    int g    = (d4 >> 3) * 4 + (k4 >> 2);
    int lhl  = ((k4 >> 1) & 1) << 5;
#pragma unroll
    for (int dd = 0; dd < 4; ++dd) {
      int lane = lhl | ((d4 & 7) * 4 + dd);
      uint2 w; w.x = pack2(c0[dd], c1[dd]); w.y = pack2(c2[dd], c3[dd]);
      *(uint2*)(tile + g * 1024 + lane * 16 + (k4 & 1) * 8) = w;
    }
  }
  __syncthreads();
#pragma unroll
  for (int i = 0; i < 4; ++i)
    *(uint4*)(out + 16384 + tid * 16 + i * 4096) =
        *(const uint4*)(tile + tid * 16 + i * 4096);
}

// ============ main attention kernel: pipelined + wave-phase stagger ============
__global__ __launch_bounds__(512, 2)
void fattn_main(const float* __restrict__ Qg, const float* __restrict__ Sg,
                const char* __restrict__ ws, float* __restrict__ Og)
{
  __shared__ __align__(16) char Kb[2][16384];   // K dbuf (gload_lds)
  __shared__ __align__(16) char Vb[3][16384];   // V triple buffer (gload_lds)

  const int tid  = threadIdx.x;
  const int wv   = tid >> 6;          // 0..7
  const int lane = tid & 63;
  const int l31  = lane & 31;
  const int h    = lane >> 5;

  // XCD/bh-grouped LPT: xcd = gi&7; deep blocks dispatched first.
  const int gi  = blockIdx.x;         // 0..511
  const int xcd = gi & 7;
  const int j   = gi >> 3;            // 0..63
  const int bh  = xcd * 8 + (j & 7);
  const int bx  = 7 - (j >> 3);
  const int b   = bh >> 4;
  const int hh  = bh & (NH - 1);
  const int q0  = bx * QT;

  const float log2e = 1.4426950408889634f;
  const float slope = Sg[hh] * log2e;               // log2-domain ALiBi slope
  const float scale = 0.08838834764831845f * log2e; // (1/sqrt(128))*log2e
  const long strideS = (long)NH * HDIM;

  // Q fragments: B-operand (col = l31 = q, k = c*16 + h*8 + j), pre-scaled
  const int q0w  = q0 + wv * QW;
  const int qrow = q0w + l31;
  const float* qp = Qg + ((long)b * SEQ + qrow) * strideS + (long)hh * HDIM;
  short8 qf[8];
#pragma unroll
  for (int c = 0; c < 8; ++c) {
    const float* p = qp + c * 16 + h * 8;
    float4 x = *(const float4*)p;
    float4 y = *(const float4*)(p + 4);
    short8 f;
    f[0]=(short)f2bf(x.x*scale); f[1]=(short)f2bf(x.y*scale);
    f[2]=(short)f2bf(x.z*scale); f[3]=(short)f2bf(x.w*scale);
    f[4]=(short)f2bf(y.x*scale); f[5]=(short)f2bf(y.y*scale);
    f[6]=(short)f2bf(y.z*scale); f[7]=(short)f2bf(y.w*scale);
    qf[c] = f;
  }

  const float q_f  = (float)qrow;
  const float qb   = slope * q_f;
  const float h4   = (float)(4 * h);
  const float s32  = slope * 32.f;

  // ones fragment (bf16 1.0) for row-sum MFMA
  short8 ones;
#pragma unroll
  for (int i = 0; i < 8; ++i) ones[i] = (short)0x3F80;

  f32x16 acc[4], lacc;
#pragma unroll
  for (int nb = 0; nb < 4; ++nb)
#pragma unroll
    for (int i = 0; i < 16; ++i) acc[nb][i] = 0.f;
#pragma unroll
  for (int i = 0; i < 16; ++i) lacc[i] = 0.f;

  const int myend = (q0w + QW - 1) / KT;
  const int ntile = 4 * bx + 4;

  const char* wsbh = ws + (long)bh * NT * TILE_BYTES;

  // ---- prologue: tile 0 -> Kb[0], Vb[0] ----
  {
    int seg = wv * 2;
#pragma unroll
    for (int sg = 0; sg < 2; ++sg) {
      gload16(wsbh + (seg + sg) * 1024 + lane * 16, &Kb[0][(seg + sg) * 1024]);
      gload16(wsbh + 16384 + (seg + sg) * 1024 + lane * 16, &Vb[0][(seg + sg) * 1024]);
    }
  }
  __syncthreads();

  short8 pa[4];          // P fragments of the PREVIOUS tile (pipeline state)
  int vcur = 0, vnx = 1; // V buffer rotation: tile t in buf t%3

  for (int t = 0; t < ntile; ++t) {
    // ---- stage tile t+1 (K -> Kb[(t+1)&1], V -> Vb[(t+1)%3]) ----
    if (t + 1 < ntile) {
      const char* src = wsbh + (long)(t + 1) * TILE_BYTES;
      char* kn = Kb[(t + 1) & 1];
      char* vn = Vb[0] + vnx * 16384;
      int seg = wv * 2;
#pragma unroll
      for (int sg = 0; sg < 2; ++sg) {
        gload16(src + (seg + sg) * 1024 + lane * 16, kn + (seg + sg) * 1024);
        gload16(src + 16384 + (seg + sg) * 1024 + lane * 16, vn + (seg + sg) * 1024);
      }
    }

    const int lb = lane * 16;
    const int k0 = t * KT;
    const int vprev = (vcur == 0) ? 2 : vcur - 1;   // (t-1)%3

    if (t == 0) {
      // ======== first tile: QK + softmax only (fills the pipeline) ========
      const char* Kc = Kb[0];
      const float base = __builtin_fmaf(slope, (float)k0 + h4, -qb);
      f32x16 s0, s1;
#pragma unroll
      for (int i = 0; i < 16; ++i) {
        float b0 = __builtin_fmaf(slope, (float)((i & 3) + 8 * (i >> 2)), base);
        s0[i] = b0; s1[i] = b0 + s32;
      }
      __builtin_amdgcn_s_setprio(1);
#pragma unroll
      for (int c = 0; c < 8; ++c) {
        short8 ka = *(const short8*)(Kc + c * 1024 + lb);
        short8 k2 = *(const short8*)(Kc + (8 + c) * 1024 + lb);
        s0 = __builtin_amdgcn_mfma_f32_32x32x16_bf16(ka, qf[c], s0, 0, 0, 0);
        s1 = __builtin_amdgcn_mfma_f32_32x32x16_bf16(k2, qf[c], s1, 0, 0, 0);
      }
      __builtin_amdgcn_s_setprio(0);
      const bool diag = (t == myend);
      const float kb0 = (float)(k0 + 4 * h) - q_f;
#pragma unroll
      for (int kc = 0; kc < 4; ++kc) {
        const int i0 = (kc & 1) * 8;
        float sv[8];
#pragma unroll
        for (int e = 0; e < 8; ++e)
          sv[e] = (kc < 2) ? s0[i0 + e] : s1[i0 + e];
        if (diag) {
          const float add32 = (kc >= 2) ? 32.f : 0.f;
#pragma unroll
          for (int e = 0; e < 8; ++e) {
            const int i = i0 + e;
            float d0 = kb0 + (float)((i & 3) + 8 * (i >> 2)) + add32;
            sv[e] = (d0 > 0.f) ? -3.0e38f : sv[e];
          }
        }
        float pc[8];
#pragma unroll
        for (int e = 0; e < 8; ++e) pc[e] = rexp2(sv[e]);
        unsigned int a0 = cvtpk(pc[0], pc[1]);
        unsigned int b0 = cvtpk(pc[4], pc[5]);
        unsigned int a1 = cvtpk(pc[2], pc[3]);
        unsigned int b1 = cvtpk(pc[6], pc[7]);
        asm volatile("v_permlane32_swap_b32 %0, %1" : "+v"(a0), "+v"(b0));
        asm volatile("v_permlane32_swap_b32 %0, %1" : "+v"(a1), "+v"(b1));
        union { unsigned int w[4]; short8 v; } u;
        u.w[0] = a0; u.w[1] = a1; u.w[2] = b0; u.w[3] = b1;
        pa[kc] = u.v;
      }
    } else if (t <= myend) {
      // ======== steady state with wave-phase stagger ========
      // Even waves: QK(t) -> PV(t-1) -> softmax(t)
      // Odd waves:  PV(t-1) -> QK(t) -> softmax(t)
      // QK and PV are mutually independent (QK reads K(t)+qf; PV reads pa+V(t-1)),
      // so both orders are legal; differing orders de-align the waves' pipe usage.
      const char* Kc = Kb[t & 1];
      const char* Vp = Vb[0] + vprev * 16384;
      const float base = __builtin_fmaf(slope, (float)k0 + h4, -qb);
      f32x16 s0, s1;
#pragma unroll
      for (int i = 0; i < 16; ++i) {
        float b0 = __builtin_fmaf(slope, (float)((i & 3) + 8 * (i >> 2)), base);
        s0[i] = b0; s1[i] = b0 + s32;
      }

      auto do_qk = [&]() {
        __builtin_amdgcn_s_setprio(1);
#pragma unroll
        for (int c = 0; c < 8; ++c) {
          short8 ka = *(const short8*)(Kc + c * 1024 + lb);
          short8 k2 = *(const short8*)(Kc + (8 + c) * 1024 + lb);
          s0 = __builtin_amdgcn_mfma_f32_32x32x16_bf16(ka, qf[c], s0, 0, 0, 0);
          s1 = __builtin_amdgcn_mfma_f32_32x32x16_bf16(k2, qf[c], s1, 0, 0, 0);
        }
        __builtin_amdgcn_s_setprio(0);
      };
      auto do_pv = [&]() {
        __builtin_amdgcn_s_setprio(1);
#pragma unroll
        for (int kc = 0; kc < 4; ++kc)
          lacc = __builtin_amdgcn_mfma_f32_32x32x16_bf16(pa[kc], ones, lacc, 0, 0, 0);
#pragma unroll
        for (int nb = 0; nb < 4; ++nb)
#pragma unroll
          for (int kc = 0; kc < 4; ++kc) {
            short8 vf = *(const short8*)(Vp + (nb * 4 + kc) * 1024 + lb);
            acc[nb] = __builtin_amdgcn_mfma_f32_32x32x16_bf16(pa[kc], vf, acc[nb], 0, 0, 0);
          }
        __builtin_amdgcn_s_setprio(0);
      };

      if ((wv & 1) == 0) { do_qk(); do_pv(); }
      else               { do_pv(); do_qk(); }

      // ---- softmax(t): raw v_exp_f32, writes pa in place ----
      const bool diag = (t == myend);
      const float kb0 = (float)(k0 + 4 * h) - q_f;
#pragma unroll
      for (int kc = 0; kc < 4; ++kc) {
        const int i0 = (kc & 1) * 8;
        float sv[8];
#pragma unroll
        for (int e = 0; e < 8; ++e)
          sv[e] = (kc < 2) ? s0[i0 + e] : s1[i0 + e];
        if (diag) {
          const float add32 = (kc >= 2) ? 32.f : 0.f;
#pragma unroll
          for (int e = 0; e < 8; ++e) {
            const int i = i0 + e;
            float d0 = kb0 + (float)((i & 3) + 8 * (i >> 2)) + add32;
            sv[e] = (d0 > 0.f) ? -3.0e38f : sv[e];
          }
        }
        float pc[8];
#pragma unroll
        for (int e = 0; e < 8; ++e) pc[e] = rexp2(sv[e]);
        unsigned int a0 = cvtpk(pc[0], pc[1]);
        unsigned int b0 = cvtpk(pc[4], pc[5]);
        unsigned int a1 = cvtpk(pc[2], pc[3]);
        unsigned int b1 = cvtpk(pc[6], pc[7]);
        asm volatile("v_permlane32_swap_b32 %0, %1" : "+v"(a0), "+v"(b0));
        asm volatile("v_permlane32_swap_b32 %0, %1" : "+v"(a1), "+v"(b1));
        union { unsigned int w[4]; short8 v; } u;
        u.w[0] = a0; u.w[1] = a1; u.w[2] = b0; u.w[3] = b1;
        pa[kc] = u.v;
      }
    } else if (t == myend + 1) {
      // ======== drain: final PV of tile myend ========
      const char* Vp = Vb[0] + vprev * 16384;
      __builtin_amdgcn_s_setprio(1);
#pragma unroll
      for (int kc = 0; kc < 4; ++kc)
        lacc = __builtin_amdgcn_mfma_f32_32x32x16_bf16(pa[kc], ones, lacc, 0, 0, 0);
#pragma unroll
      for (int nb = 0; nb < 4; ++nb)
#pragma unroll
        for (int kc = 0; kc < 4; ++kc) {
          short8 vf = *(const short8*)(Vp + (nb * 4 + kc) * 1024 + lb);
          acc[nb] = __builtin_amdgcn_mfma_f32_32x32x16_bf16(pa[kc], vf, acc[nb], 0, 0, 0);
        }
      __builtin_amdgcn_s_setprio(0);
    }

    __syncthreads();   // buffer handoff + vmcnt drain
    vcur = vnx; vnx = (vnx == 2) ? 0 : vnx + 1;
  }

  // ---- post-loop drain for waves whose diagonal tile is the last staged ----
  if (myend == ntile - 1) {
    const int lb = lane * 16;
    const char* Vp = Vb[0] + ((ntile - 1) % 3) * 16384;
#pragma unroll
    for (int kc = 0; kc < 4; ++kc)
      lacc = __builtin_amdgcn_mfma_f32_32x32x16_bf16(pa[kc], ones, lacc, 0, 0, 0);
#pragma unroll
    for (int nb = 0; nb < 4; ++nb)
#pragma unroll
      for (int kc = 0; kc < 4; ++kc) {
        short8 vf = *(const short8*)(Vp + (nb * 4 + kc) * 1024 + lb);
        acc[nb] = __builtin_amdgcn_mfma_f32_32x32x16_bf16(pa[kc], vf, acc[nb], 0, 0, 0);
      }
  }

  // ---- epilogue: O / l ----
  float* op = Og + ((long)b * SEQ + q0w) * strideS + (long)hh * HDIM;
#pragma unroll
  for (int i = 0; i < 16; ++i) {
    int qr = (i & 3) + 8 * (i >> 2) + 4 * h;
    float iv = 1.0f / lacc[i];
    long rb = (long)qr * strideS;
#pragma unroll
    for (int nb = 0; nb < 4; ++nb)
      op[rb + nb * 32 + l31] = acc[nb][i] * iv;
  }
}

// ============ fallback (round-2 kernel, proven): used if ws too small ============
__global__ __launch_bounds__(256, 2)
void fattn_fb(const float* __restrict__ Qg, const float* __restrict__ Kg,
              const float* __restrict__ Vg, const float* __restrict__ Sg,
              float* __restrict__ Og)
{
  __shared__ __align__(16) char Ks[KT * HDIM * 2];
  __shared__ __align__(16) char Vs[HDIM * KT * 2];
  const int tid  = threadIdx.x;
  const int wv   = tid >> 6;
  const int lane = tid & 63;
  const int l31  = lane & 31;
  const int h    = lane >> 5;
  const int q0 = blockIdx.x * 128;
  const int bh = blockIdx.y;
  const int b  = bh >> 4;
  const int hh = bh & (NH - 1);
  const float slope = Sg[hh];
  const float scale = 0.08838834764831845f;
  const long strideS = (long)NH * HDIM;
  const int q0w  = q0 + wv * QW;
  const int qrow = q0w + l31;
  const float* qp = Qg + ((long)b * SEQ + qrow) * strideS + (long)hh * HDIM;
  short8 qf[8];
#pragma unroll
  for (int c = 0; c < 8; ++c) {
    const float* p = qp + c * 16 + h * 8;
    float4 x = *(const float4*)p;
    float4 y = *(const float4*)(p + 4);
    short8 f;
    f[0]=(short)f2bf(x.x*scale); f[1]=(short)f2bf(x.y*scale);
    f[2]=(short)f2bf(x.z*scale); f[3]=(short)f2bf(x.w*scale);
    f[4]=(short)f2bf(y.x*scale); f[5]=(short)f2bf(y.y*scale);
    f[6]=(short)f2bf(y.z*scale); f[7]=(short)f2bf(y.w*scale);
    qf[c] = f;
  }
  float m_run = -1e30f, l_run = 0.f;
  f32x16 acc[4];
#pragma unroll
  for (int nb = 0; nb < 4; ++nb)
#pragma unroll
    for (int i = 0; i < 16; ++i) acc[nb][i] = 0.f;
  const float* kb = Kg + (long)b * SEQ * strideS + (long)hh * HDIM;
  const float* vb = Vg + (long)b * SEQ * strideS + (long)hh * HDIM;
  const float q_f = (float)qrow;
  const int myend = (q0w + QW - 1) / KT;
  const int ntile = q0 / KT + 2;
  for (int t = 0; t < ntile; ++t) {
    const int k0 = t * KT;
    __syncthreads();
#pragma unroll
    for (int i = 0; i < 8; ++i) {
      int f4 = tid + i * 256;
      int row = f4 >> 5, c4 = f4 & 31;
      float4 x = *(const float4*)(kb + (long)(k0 + row) * strideS + c4 * 4);
      uint2 w; w.x = pack2(x.x, x.y); w.y = pack2(x.z, x.w);
      int byt = (row * 256 + c4 * 8) ^ ((row & 7) << 4);
      *(uint2*)(Ks + byt) = w;
    }
#pragma unroll
    for (int i = 0; i < 2; ++i) {
      int blk = tid + i * 256;
      int d4 = blk & 31, k4 = blk >> 5;
      const float* vp = vb + (long)(k0 + k4 * 4) * strideS + d4 * 4;
      float4 r0 = *(const float4*)vp;
      float4 r1 = *(const float4*)(vp + strideS);
      float4 r2 = *(const float4*)(vp + 2 * strideS);
      float4 r3 = *(const float4*)(vp + 3 * strideS);
      const float c0[4] = {r0.x, r0.y, r0.z, r0.w};
      const float c1[4] = {r1.x, r1.y, r1.z, r1.w};
      const float c2[4] = {r2.x, r2.y, r2.z, r2.w};
      const float c3[4] = {r3.x, r3.y, r3.z, r3.w};
#pragma unroll
      for (int dd = 0; dd < 4; ++dd) {
        int d = d4 * 4 + dd;
        uint2 w; w.x = pack2(c0[dd], c1[dd]); w.y = pack2(c2[dd], c3[dd]);
        int byt = (d * (KT * 2) + k4 * 8) ^ ((d & 7) << 4);
        *(uint2*)(Vs + byt) = w;
      }
    }
    __syncthreads();
    if (t <= myend) {
      f32x16 s0, s1;
#pragma unroll
      for (int i = 0; i < 16; ++i) { s0[i] = 0.f; s1[i] = 0.f; }
      const int swzk = (l31 & 7) << 4;
#pragma unroll
      for (int c = 0; c < 8; ++c) {
        int colb = c * 32 + h * 16;
        short8 ka = *(const short8*)(Ks + ((l31 * 256 + colb) ^ swzk));
        short8 kbf = *(const short8*)(Ks + (((l31 + 32) * 256 + colb) ^ swzk));
        s0 = __builtin_amdgcn_mfma_f32_32x32x16_bf16(ka, qf[c], s0, 0, 0, 0);
        s1 = __builtin_amdgcn_mfma_f32_32x32x16_bf16(kbf, qf[c], s1, 0, 0, 0);
      }
      float p[32];
      float pm = -1e30f;
#pragma unroll
      for (int i = 0; i < 16; ++i) {
        float kp0 = (float)(k0 + (i & 3) + 8 * (i >> 2) + 4 * h);
        float d0 = kp0 - q_f;
        float v0 = s0[i] + slope * d0;
        v0 = (d0 > 0.f) ? -1e30f : v0;
        p[i] = v0;
        float d1 = d0 + 32.f;
        float v1 = s1[i] + slope * d1;
        v1 = (d1 > 0.f) ? -1e30f : v1;
        p[16 + i] = v1;
        pm = fmaxf(pm, fmaxf(v0, v1));
      }
      pm = fmaxf(pm, __shfl_xor(pm, 32));
      if (!__all(pm <= m_run)) {
        float M = fmaxf(m_run, pm);
        float alpha = __expf(m_run - M);
        m_run = M;
#pragma unroll
        for (int i = 0; i < 16; ++i) {
          int qr = (i & 3) + 8 * (i >> 2) + 4 * h;
          float al = __shfl(alpha, qr, 64);
          acc[0][i] *= al; acc[1][i] *= al; acc[2][i] *= al; acc[3][i] *= al;
        }
        l_run *= alpha;
      }
      float ps = 0.f;
#pragma unroll
      for (int i = 0; i < 32; ++i) {
        float e = __expf(p[i] - m_run);
        p[i] = e;
        ps += e;
      }
      ps += __shfl_xor(ps, 32);
      l_run += ps;
      short8 pa[4];
#pragma unroll
      for (int kc = 0; kc < 4; ++kc) {
        const int base = kc * 8;
        unsigned int a0 = cvtpk(p[base + 0], p[base + 1]);
        unsigned int b0 = cvtpk(p[base + 4], p[base + 5]);
        unsigned int a1 = cvtpk(p[base + 2], p[base + 3]);
        unsigned int b1 = cvtpk(p[base + 6], p[base + 7]);
        asm volatile("v_permlane32_swap_b32 %0, %1" : "+v"(a0), "+v"(b0));
        asm volatile("v_permlane32_swap_b32 %0, %1" : "+v"(a1), "+v"(b1));
        union { unsigned int w[4]; short8 v; } u;
        u.w[0] = a0; u.w[1] = a1; u.w[2] = b0; u.w[3] = b1;
        pa[kc] = u.v;
      }
#pragma unroll
      for (int nb = 0; nb < 4; ++nb) {
        int rowb = (nb * 32 + l31) * (KT * 2);
        int sw = ((nb * 32 + l31) & 7) << 4;
#pragma unroll
        for (int kc = 0; kc < 4; ++kc) {
          short8 vf = *(const short8*)(Vs + ((rowb + kc * 32 + h * 16) ^ sw));
          acc[nb] = __builtin_amdgcn_mfma_f32_32x32x16_bf16(pa[kc], vf, acc[nb], 0, 0, 0);
        }
      }
    }
  }
  float inv = 1.0f / l_run;
  float* op = Og + ((long)b * SEQ + q0w) * strideS + (long)hh * HDIM;
#pragma unroll
  for (int i = 0; i < 16; ++i) {
    int qr = (i & 3) + 8 * (i >> 2) + 4 * h;
    float iv = __shfl(inv, qr, 64);
    long rb = (long)qr * strideS;
#pragma unroll
    for (int nb = 0; nb < 4; ++nb)
      op[rb + nb * 32 + l31] = acc[nb][i] * iv;
  }
}

extern "C" void kernel_launch(void* const* d_in, const int* in_sizes, int n_in,
                              void* d_out, int out_size, void* d_ws, size_t ws_size,
                              hipStream_t stream) {
  const float* Q = (const float*)d_in[0];
  const float* K = (const float*)d_in[1];
  const float* V = (const float*)d_in[2];
  const float* S = (const float*)d_in[3];
  float* O = (float*)d_out;
  if (ws_size >= WS_NEEDED) {
    prepass<<<dim3(NT, B_N * NH), 256, 0, stream>>>(K, V, (char*)d_ws);
    fattn_main<<<dim3((SEQ / QT) * B_N * NH), 512, 0, stream>>>(Q, S, (const char*)d_ws, O);
  } else {
    fattn_fb<<<dim3(SEQ / 128, B_N * NH), 256, 0, stream>>>(Q, K, V, S, O);
  }
}

// Round 12
// 129.799 us; speedup vs baseline: 1.0068x; 1.0068x over previous
//
#include <hip/hip_runtime.h>
#include <hip/hip_bf16.h>

typedef __attribute__((ext_vector_type(8))) short short8;
typedef __attribute__((ext_vector_type(16))) float f32x16;

#define B_N 4
#define SEQ 2048
#define NH 16
#define HDIM 128
#define QT 128      // q rows per block (4 waves x 32) -> 2 async blocks/CU
#define QW 32       // q rows per wave
#define KT 64       // k tile
#define NT (SEQ / KT)            // 32 tiles
#define TILE_BYTES 32768         // 16KB K frags + 16KB V frags
#define WS_NEEDED ((size_t)B_N * NH * NT * TILE_BYTES)   // 67,108,864 B

static __device__ __forceinline__ unsigned short f2bf(float f) {
  union { __hip_bfloat16 h; unsigned short u; } cv;
  cv.h = __float2bfloat16(f);
  return cv.u;
}
static __device__ __forceinline__ unsigned int pack2(float a, float b) {
  return (unsigned int)f2bf(a) | ((unsigned int)f2bf(b) << 16);
}
static __device__ __forceinline__ unsigned int cvtpk(float lo, float hi) {
  unsigned int r;
  asm("v_cvt_pk_bf16_f32 %0, %1, %2" : "=v"(r) : "v"(lo), "v"(hi));
  return r;
}
// raw v_exp_f32 (log2-domain exp); OCML exp2f adds range-fixup VALU we don't need.
static __device__ __forceinline__ float rexp2(float x) {
  return __builtin_amdgcn_exp2f(x);
}
static __device__ __forceinline__ void gload16(const void* g, void* l) {
  __builtin_amdgcn_global_load_lds(
      (const __attribute__((address_space(1))) unsigned int*)g,
      (__attribute__((address_space(3))) unsigned int*)l, 16, 0, 0);
}

// ============ pre-pass: K,V fp32 -> bf16 fragment-major tiles in ws ============
// Tile image (32 KB): [16 K-frags][16 V-frags], each frag 1 KB = 64 lanes x 16B.
__global__ __launch_bounds__(256)
void prepass(const float* __restrict__ Kg, const float* __restrict__ Vg,
             char* __restrict__ ws)
{
  __shared__ __align__(16) char tile[16384];
  const int t  = blockIdx.x;        // 0..NT-1
  const int bh = blockIdx.y;        // 0..63
  const int b  = bh >> 4, hh = bh & (NH - 1);
  const int tid = threadIdx.x;
  const long strideS = (long)NH * HDIM;
  const float* kb = Kg + ((long)b * SEQ + t * KT) * strideS + (long)hh * HDIM;
  const float* vb = Vg + ((long)b * SEQ + t * KT) * strideS + (long)hh * HDIM;
  char* out = ws + ((long)bh * NT + t) * TILE_BYTES;

  // ---- K half ----
#pragma unroll
  for (int i = 0; i < 8; ++i) {
    int f4 = tid + i * 256;            // 0..2047
    int row = f4 >> 5, c4 = f4 & 31;   // row 0..63, float4-col 0..31
    float4 x = *(const float4*)(kb + (long)row * strideS + c4 * 4);
    uint2 w; w.x = pack2(x.x, x.y); w.y = pack2(x.z, x.w);
    int f    = (row >> 5) * 8 + (c4 >> 2);
    int lane = (((c4 >> 1) & 1) << 5) | (row & 31);
    *(uint2*)(tile + f * 1024 + lane * 16 + (c4 & 1) * 8) = w;
  }
  __syncthreads();
#pragma unroll
  for (int i = 0; i < 4; ++i)
    *(uint4*)(out + tid * 16 + i * 4096) = *(const uint4*)(tile + tid * 16 + i * 4096);
  __syncthreads();

  // ---- V half (transpose via 4x4 blocks) ----
#pragma unroll
  for (int i = 0; i < 2; ++i) {
    int blk = tid + i * 256;           // 0..511
    int d4 = blk & 31, k4 = blk >> 5;  // d-block 0..31, k-block 0..15
    const float* vp = vb + (long)(k4 * 4) * strideS + d4 * 4;
    float4 r0 = *(const float4*)vp;
    float4 r1 = *(const float4*)(vp + strideS);
    float4 r2 = *(const float4*)(vp + 2 * strideS);
    float4 r3 = *(const float4*)(vp + 3 * strideS);
    const float c0[4] = {r0.x, r0.y, r0.z, r0.w};
    const float c1[4] = {r1.x, r1.y, r1.z, r1.w};
    const float c2[4] = {r2.x, r2.y, r2.z, r2.w};
    const float c3[4] = {r3.x, r3.y, r3.z, r3.w};
    int g    = (d4 >> 3) * 4 + (k4 >> 2);
    int lhl  = ((k4 >> 1) & 1) << 5;
#pragma unroll
    for (int dd = 0; dd < 4; ++dd) {
      int lane = lhl | ((d4 & 7) * 4 + dd);
      uint2 w; w.x = pack2(c0[dd], c1[dd]); w.y = pack2(c2[dd], c3[dd]);
      *(uint2*)(tile + g * 1024 + lane * 16 + (k4 & 1) * 8) = w;
    }
  }
  __syncthreads();
#pragma unroll
  for (int i = 0; i < 4; ++i)
    *(uint4*)(out + 16384 + tid * 16 + i * 4096) =
        *(const uint4*)(tile + tid * 16 + i * 4096);
}

// ============ main kernel: round-9 core, 4 waves/block, 2 async blocks/CU ============
__global__ __launch_bounds__(256, 2)
void fattn_main(const float* __restrict__ Qg, const float* __restrict__ Sg,
                const char* __restrict__ ws, float* __restrict__ Og)
{
  __shared__ __align__(16) char Kb[2][16384];   // K dbuf (gload_lds)
  __shared__ __align__(16) char Vb[3][16384];   // V triple buffer (gload_lds)

  const int tid  = threadIdx.x;
  const int wv   = tid >> 6;          // 0..3
  const int lane = tid & 63;
  const int l31  = lane & 31;
  const int h    = lane >> 5;

  // XCD/bh-grouped LPT: xcd = gi&7; deep blocks (bx=15) dispatched first.
  const int gi  = blockIdx.x;         // 0..1023
  const int xcd = gi & 7;
  const int j   = gi >> 3;            // 0..127
  const int bh  = xcd * 8 + (j & 7);
  const int bx  = 15 - (j >> 3);      // 0..15
  const int b   = bh >> 4;
  const int hh  = bh & (NH - 1);
  const int q0  = bx * QT;

  const float log2e = 1.4426950408889634f;
  const float slope = Sg[hh] * log2e;               // log2-domain ALiBi slope
  const float scale = 0.08838834764831845f * log2e; // (1/sqrt(128))*log2e
  const long strideS = (long)NH * HDIM;

  // Q fragments: B-operand (col = l31 = q, k = c*16 + h*8 + j), pre-scaled
  const int q0w  = q0 + wv * QW;
  const int qrow = q0w + l31;
  const float* qp = Qg + ((long)b * SEQ + qrow) * strideS + (long)hh * HDIM;
  short8 qf[8];
#pragma unroll
  for (int c = 0; c < 8; ++c) {
    const float* p = qp + c * 16 + h * 8;
    float4 x = *(const float4*)p;
    float4 y = *(const float4*)(p + 4);
    short8 f;
    f[0]=(short)f2bf(x.x*scale); f[1]=(short)f2bf(x.y*scale);
    f[2]=(short)f2bf(x.z*scale); f[3]=(short)f2bf(x.w*scale);
    f[4]=(short)f2bf(y.x*scale); f[5]=(short)f2bf(y.y*scale);
    f[6]=(short)f2bf(y.z*scale); f[7]=(short)f2bf(y.w*scale);
    qf[c] = f;
  }

  const float q_f  = (float)qrow;
  const float qb   = slope * q_f;
  const float h4   = (float)(4 * h);
  const float s32  = slope * 32.f;

  // ones fragment (bf16 1.0) for row-sum MFMA
  short8 ones;
#pragma unroll
  for (int i = 0; i < 8; ++i) ones[i] = (short)0x3F80;

  f32x16 acc[4], lacc;
#pragma unroll
  for (int nb = 0; nb < 4; ++nb)
#pragma unroll
    for (int i = 0; i < 16; ++i) acc[nb][i] = 0.f;
#pragma unroll
  for (int i = 0; i < 16; ++i) lacc[i] = 0.f;

  const int myend = (q0w + QW - 1) / KT;
  const int ntile = q0 / KT + 2;      // 2*bx + 2

  const char* wsbh = ws + (long)bh * NT * TILE_BYTES;

  // ---- prologue: tile 0 -> Kb[0], Vb[0] (4 waves x 4 segs each) ----
  {
    int seg = wv * 4;
#pragma unroll
    for (int sg = 0; sg < 4; ++sg) {
      gload16(wsbh + (seg + sg) * 1024 + lane * 16, &Kb[0][(seg + sg) * 1024]);
      gload16(wsbh + 16384 + (seg + sg) * 1024 + lane * 16, &Vb[0][(seg + sg) * 1024]);
    }
  }
  __syncthreads();

  short8 pa[4];          // P fragments of the PREVIOUS tile (pipeline state)
  int vcur = 0, vnx = 1; // V buffer rotation: tile t in buf t%3

  for (int t = 0; t < ntile; ++t) {
    // ---- stage tile t+1 (K -> Kb[(t+1)&1], V -> Vb[(t+1)%3]) ----
    if (t + 1 < ntile) {
      const char* src = wsbh + (long)(t + 1) * TILE_BYTES;
      char* kn = Kb[(t + 1) & 1];
      char* vn = Vb[0] + vnx * 16384;
      int seg = wv * 4;
#pragma unroll
      for (int sg = 0; sg < 4; ++sg) {
        gload16(src + (seg + sg) * 1024 + lane * 16, kn + (seg + sg) * 1024);
        gload16(src + 16384 + (seg + sg) * 1024 + lane * 16, vn + (seg + sg) * 1024);
      }
    }

    const int lb = lane * 16;
    const int k0 = t * KT;
    const int vprev = (vcur == 0) ? 2 : vcur - 1;   // (t-1)%3

    if (t == 0) {
      // ======== first tile: QK + softmax only (fills the pipeline) ========
      const char* Kc = Kb[0];
      const float base = __builtin_fmaf(slope, (float)k0 + h4, -qb);
      f32x16 s0, s1;
#pragma unroll
      for (int i = 0; i < 16; ++i) {
        float b0 = __builtin_fmaf(slope, (float)((i & 3) + 8 * (i >> 2)), base);
        s0[i] = b0; s1[i] = b0 + s32;
      }
      __builtin_amdgcn_s_setprio(1);
#pragma unroll
      for (int c = 0; c < 8; ++c) {
        short8 ka = *(const short8*)(Kc + c * 1024 + lb);
        short8 k2 = *(const short8*)(Kc + (8 + c) * 1024 + lb);
        s0 = __builtin_amdgcn_mfma_f32_32x32x16_bf16(ka, qf[c], s0, 0, 0, 0);
        s1 = __builtin_amdgcn_mfma_f32_32x32x16_bf16(k2, qf[c], s1, 0, 0, 0);
      }
      __builtin_amdgcn_s_setprio(0);
      const bool diag = (t == myend);
      const float kb0 = (float)(k0 + 4 * h) - q_f;
#pragma unroll
      for (int kc = 0; kc < 4; ++kc) {
        const int i0 = (kc & 1) * 8;
        float sv[8];
#pragma unroll
        for (int e = 0; e < 8; ++e)
          sv[e] = (kc < 2) ? s0[i0 + e] : s1[i0 + e];
        if (diag) {
          const float add32 = (kc >= 2) ? 32.f : 0.f;
#pragma unroll
          for (int e = 0; e < 8; ++e) {
            const int i = i0 + e;
            float d0 = kb0 + (float)((i & 3) + 8 * (i >> 2)) + add32;
            sv[e] = (d0 > 0.f) ? -3.0e38f : sv[e];
          }
        }
        float pc[8];
#pragma unroll
        for (int e = 0; e < 8; ++e) pc[e] = rexp2(sv[e]);
        unsigned int a0 = cvtpk(pc[0], pc[1]);
        unsigned int b0 = cvtpk(pc[4], pc[5]);
        unsigned int a1 = cvtpk(pc[2], pc[3]);
        unsigned int b1 = cvtpk(pc[6], pc[7]);
        asm volatile("v_permlane32_swap_b32 %0, %1" : "+v"(a0), "+v"(b0));
        asm volatile("v_permlane32_swap_b32 %0, %1" : "+v"(a1), "+v"(b1));
        union { unsigned int w[4]; short8 v; } u;
        u.w[0] = a0; u.w[1] = a1; u.w[2] = b0; u.w[3] = b1;
        pa[kc] = u.v;
      }
    } else if (t <= myend) {
      // ======== steady state: QK(t) -> PV(t-1) -> softmax(t) overwrites pa ====
      const char* Kc = Kb[t & 1];
      const char* Vp = Vb[0] + vprev * 16384;
      const float base = __builtin_fmaf(slope, (float)k0 + h4, -qb);
      f32x16 s0, s1;
#pragma unroll
      for (int i = 0; i < 16; ++i) {
        float b0 = __builtin_fmaf(slope, (float)((i & 3) + 8 * (i >> 2)), base);
        s0[i] = b0; s1[i] = b0 + s32;
      }
      __builtin_amdgcn_s_setprio(1);
#pragma unroll
      for (int c = 0; c < 8; ++c) {
        short8 ka = *(const short8*)(Kc + c * 1024 + lb);
        short8 k2 = *(const short8*)(Kc + (8 + c) * 1024 + lb);
        s0 = __builtin_amdgcn_mfma_f32_32x32x16_bf16(ka, qf[c], s0, 0, 0, 0);
        s1 = __builtin_amdgcn_mfma_f32_32x32x16_bf16(k2, qf[c], s1, 0, 0, 0);
      }
      // ---- PV(t-1) + lacc(t-1) (uses pa + V(t-1); independent of s0/s1) ----
#pragma unroll
      for (int kc = 0; kc < 4; ++kc)
        lacc = __builtin_amdgcn_mfma_f32_32x32x16_bf16(pa[kc], ones, lacc, 0, 0, 0);
#pragma unroll
      for (int nb = 0; nb < 4; ++nb)
#pragma unroll
        for (int kc = 0; kc < 4; ++kc) {
          short8 vf = *(const short8*)(Vp + (nb * 4 + kc) * 1024 + lb);
          acc[nb] = __builtin_amdgcn_mfma_f32_32x32x16_bf16(pa[kc], vf, acc[nb], 0, 0, 0);
        }
      __builtin_amdgcn_s_setprio(0);

      // ---- softmax(t): raw v_exp_f32, writes pa in place ----
      const bool diag = (t == myend);
      const float kb0 = (float)(k0 + 4 * h) - q_f;
#pragma unroll
      for (int kc = 0; kc < 4; ++kc) {
        const int i0 = (kc & 1) * 8;
        float sv[8];
#pragma unroll
        for (int e = 0; e < 8; ++e)
          sv[e] = (kc < 2) ? s0[i0 + e] : s1[i0 + e];
        if (diag) {
          const float add32 = (kc >= 2) ? 32.f : 0.f;
#pragma unroll
          for (int e = 0; e < 8; ++e) {
            const int i = i0 + e;
            float d0 = kb0 + (float)((i & 3) + 8 * (i >> 2)) + add32;
            sv[e] = (d0 > 0.f) ? -3.0e38f : sv[e];
          }
        }
        float pc[8];
#pragma unroll
        for (int e = 0; e < 8; ++e) pc[e] = rexp2(sv[e]);
        unsigned int a0 = cvtpk(pc[0], pc[1]);
        unsigned int b0 = cvtpk(pc[4], pc[5]);
        unsigned int a1 = cvtpk(pc[2], pc[3]);
        unsigned int b1 = cvtpk(pc[6], pc[7]);
        asm volatile("v_permlane32_swap_b32 %0, %1" : "+v"(a0), "+v"(b0));
        asm volatile("v_permlane32_swap_b32 %0, %1" : "+v"(a1), "+v"(b1));
        union { unsigned int w[4]; short8 v; } u;
        u.w[0] = a0; u.w[1] = a1; u.w[2] = b0; u.w[3] = b1;
        pa[kc] = u.v;
      }
    } else if (t == myend + 1) {
      // ======== drain: final PV of tile myend ========
      const char* Vp = Vb[0] + vprev * 16384;
      __builtin_amdgcn_s_setprio(1);
#pragma unroll
      for (int kc = 0; kc < 4; ++kc)
        lacc = __builtin_amdgcn_mfma_f32_32x32x16_bf16(pa[kc], ones, lacc, 0, 0, 0);
#pragma unroll
      for (int nb = 0; nb < 4; ++nb)
#pragma unroll
        for (int kc = 0; kc < 4; ++kc) {
          short8 vf = *(const short8*)(Vp + (nb * 4 + kc) * 1024 + lb);
          acc[nb] = __builtin_amdgcn_mfma_f32_32x32x16_bf16(pa[kc], vf, acc[nb], 0, 0, 0);
        }
      __builtin_amdgcn_s_setprio(0);
    }

    __syncthreads();   // buffer handoff + vmcnt drain
    vcur = vnx; vnx = (vnx == 2) ? 0 : vnx + 1;
  }

  // ---- post-loop drain for waves whose diagonal tile is the last staged ----
  if (myend == ntile - 1) {
    const int lb = lane * 16;
    const char* Vp = Vb[0] + ((ntile - 1) % 3) * 16384;
#pragma unroll
    for (int kc = 0; kc < 4; ++kc)
      lacc = __builtin_amdgcn_mfma_f32_32x32x16_bf16(pa[kc], ones, lacc, 0, 0, 0);
#pragma unroll
    for (int nb = 0; nb < 4; ++nb)
#pragma unroll
      for (int kc = 0; kc < 4; ++kc) {
        short8 vf = *(const short8*)(Vp + (nb * 4 + kc) * 1024 + lb);
        acc[nb] = __builtin_amdgcn_mfma_f32_32x32x16_bf16(pa[kc], vf, acc[nb], 0, 0, 0);
      }
  }

  // ---- epilogue: O / l ----
  float* op = Og + ((long)b * SEQ + q0w) * strideS + (long)hh * HDIM;
#pragma unroll
  for (int i = 0; i < 16; ++i) {
    int qr = (i & 3) + 8 * (i >> 2) + 4 * h;
    float iv = 1.0f / lacc[i];
    long rb = (long)qr * strideS;
#pragma unroll
    for (int nb = 0; nb < 4; ++nb)
      op[rb + nb * 32 + l31] = acc[nb][i] * iv;
  }
}

// ============ fallback (round-2 kernel, proven): used if ws too small ============
__global__ __launch_bounds__(256, 2)
void fattn_fb(const float* __restrict__ Qg, const float* __restrict__ Kg,
              const float* __restrict__ Vg, const float* __restrict__ Sg,
              float* __restrict__ Og)
{
  __shared__ __align__(16) char Ks[KT * HDIM * 2];
  __shared__ __align__(16) char Vs[HDIM * KT * 2];
  const int tid  = threadIdx.x;
  const int wv   = tid >> 6;
  const int lane = tid & 63;
  const int l31  = lane & 31;
  const int h    = lane >> 5;
  const int q0 = blockIdx.x * 128;
  const int bh = blockIdx.y;
  const int b  = bh >> 4;
  const int hh = bh & (NH - 1);
  const float slope = Sg[hh];
  const float scale = 0.08838834764831845f;
  const long strideS = (long)NH * HDIM;
  const int q0w  = q0 + wv * QW;
  const int qrow = q0w + l31;
  const float* qp = Qg + ((long)b * SEQ + qrow) * strideS + (long)hh * HDIM;
  short8 qf[8];
#pragma unroll
  for (int c = 0; c < 8; ++c) {
    const float* p = qp + c * 16 + h * 8;
    float4 x = *(const float4*)p;
    float4 y = *(const float4*)(p + 4);
    short8 f;
    f[0]=(short)f2bf(x.x*scale); f[1]=(short)f2bf(x.y*scale);
    f[2]=(short)f2bf(x.z*scale); f[3]=(short)f2bf(x.w*scale);
    f[4]=(short)f2bf(y.x*scale); f[5]=(short)f2bf(y.y*scale);
    f[6]=(short)f2bf(y.z*scale); f[7]=(short)f2bf(y.w*scale);
    qf[c] = f;
  }
  float m_run = -1e30f, l_run = 0.f;
  f32x16 acc[4];
#pragma unroll
  for (int nb = 0; nb < 4; ++nb)
#pragma unroll
    for (int i = 0; i < 16; ++i) acc[nb][i] = 0.f;
  const float* kb = Kg + (long)b * SEQ * strideS + (long)hh * HDIM;
  const float* vb = Vg + (long)b * SEQ * strideS + (long)hh * HDIM;
  const float q_f = (float)qrow;
  const int myend = (q0w + QW - 1) / KT;
  const int ntile = q0 / KT + 2;
  for (int t = 0; t < ntile; ++t) {
    const int k0 = t * KT;
    __syncthreads();
#pragma unroll
    for (int i = 0; i < 8; ++i) {
      int f4 = tid + i * 256;
      int row = f4 >> 5, c4 = f4 & 31;
      float4 x = *(const float4*)(kb + (long)(k0 + row) * strideS + c4 * 4);
      uint2 w; w.x = pack2(x.x, x.y); w.y = pack2(x.z, x.w);
      int byt = (row * 256 + c4 * 8) ^ ((row & 7) << 4);
      *(uint2*)(Ks + byt) = w;
    }
#pragma unroll
    for (int i = 0; i < 2; ++i) {
      int blk = tid + i * 256;
      int d4 = blk & 31, k4 = blk >> 5;
      const float* vp = vb + (long)(k0 + k4 * 4) * strideS + d4 * 4;
      float4 r0 = *(const float4*)vp;
      float4 r1 = *(const float4*)(vp + strideS);
      float4 r2 = *(const float4*)(vp + 2 * strideS);
      float4 r3 = *(const float4*)(vp + 3 * strideS);
      const float c0[4] = {r0.x, r0.y, r0.z, r0.w};
      const float c1[4] = {r1.x, r1.y, r1.z, r1.w};
      const float c2[4] = {r2.x, r2.y, r2.z, r2.w};
      const float c3[4] = {r3.x, r3.y, r3.z, r3.w};
#pragma unroll
      for (int dd = 0; dd < 4; ++dd) {
        int d = d4 * 4 + dd;
        uint2 w; w.x = pack2(c0[dd], c1[dd]); w.y = pack2(c2[dd], c3[dd]);
        int byt = (d * (KT * 2) + k4 * 8) ^ ((d & 7) << 4);
        *(uint2*)(Vs + byt) = w;
      }
    }
    __syncthreads();
    if (t <= myend) {
      f32x16 s0, s1;
#pragma unroll
      for (int i = 0; i < 16; ++i) { s0[i] = 0.f; s1[i] = 0.f; }
      const int swzk = (l31 & 7) << 4;
#pragma unroll
      for (int c = 0; c < 8; ++c) {
        int colb = c * 32 + h * 16;
        short8 ka = *(const short8*)(Ks + ((l31 * 256 + colb) ^ swzk));
        short8 kbf = *(const short8*)(Ks + (((l31 + 32) * 256 + colb) ^ swzk));
        s0 = __builtin_amdgcn_mfma_f32_32x32x16_bf16(ka, qf[c], s0, 0, 0, 0);
        s1 = __builtin_amdgcn_mfma_f32_32x32x16_bf16(kbf, qf[c], s1, 0, 0, 0);
      }
      float p[32];
      float pm = -1e30f;
#pragma unroll
      for (int i = 0; i < 16; ++i) {
        float kp0 = (float)(k0 + (i & 3) + 8 * (i >> 2) + 4 * h);
        float d0 = kp0 - q_f;
        float v0 = s0[i] + slope * d0;
        v0 = (d0 > 0.f) ? -1e30f : v0;
        p[i] = v0;
        float d1 = d0 + 32.f;
        float v1 = s1[i] + slope * d1;
        v1 = (d1 > 0.f) ? -1e30f : v1;
        p[16 + i] = v1;
        pm = fmaxf(pm, fmaxf(v0, v1));
      }
      pm = fmaxf(pm, __shfl_xor(pm, 32));
      if (!__all(pm <= m_run)) {
        float M = fmaxf(m_run, pm);
        float alpha = __expf(m_run - M);
        m_run = M;
#pragma unroll
        for (int i = 0; i < 16; ++i) {
          int qr = (i & 3) + 8 * (i >> 2) + 4 * h;
          float al = __shfl(alpha, qr, 64);
          acc[0][i] *= al; acc[1][i] *= al; acc[2][i] *= al; acc[3][i] *= al;
        }
        l_run *= alpha;
      }
      float ps = 0.f;
#pragma unroll
      for (int i = 0; i < 32; ++i) {
        float e = __expf(p[i] - m_run);
        p[i] = e;
        ps += e;
      }
      ps += __shfl_xor(ps, 32);
      l_run += ps;
      short8 pa[4];
#pragma unroll
      for (int kc = 0; kc < 4; ++kc) {
        const int base = kc * 8;
        unsigned int a0 = cvtpk(p[base + 0], p[base + 1]);
        unsigned int b0 = cvtpk(p[base + 4], p[base + 5]);
        unsigned int a1 = cvtpk(p[base + 2], p[base + 3]);
        unsigned int b1 = cvtpk(p[base + 6], p[base + 7]);
        asm volatile("v_permlane32_swap_b32 %0, %1" : "+v"(a0), "+v"(b0));
        asm volatile("v_permlane32_swap_b32 %0, %1" : "+v"(a1), "+v"(b1));
        union { unsigned int w[4]; short8 v; } u;
        u.w[0] = a0; u.w[1] = a1; u.w[2] = b0; u.w[3] = b1;
        pa[kc] = u.v;
      }
#pragma unroll
      for (int nb = 0; nb < 4; ++nb) {
        int rowb = (nb * 32 + l31) * (KT * 2);
        int sw = ((nb * 32 + l31) & 7) << 4;
#pragma unroll
        for (int kc = 0; kc < 4; ++kc) {
          short8 vf = *(const short8*)(Vs + ((rowb + kc * 32 + h * 16) ^ sw));
          acc[nb] = __builtin_amdgcn_mfma_f32_32x32x16_bf16(pa[kc], vf, acc[nb], 0, 0, 0);
        }
      }
    }
  }
  float inv = 1.0f / l_run;
  float* op = Og + ((long)b * SEQ + q0w) * strideS + (long)hh * HDIM;
#pragma unroll
  for (int i = 0; i < 16; ++i) {
    int qr = (i & 3) + 8 * (i >> 2) + 4 * h;
    float iv = __shfl(inv, qr, 64);
    long rb = (long)qr * strideS;
#pragma unroll
    for (int nb = 0; nb < 4; ++nb)
      op[rb + nb * 32 + l31] = acc[nb][i] * iv;
  }
}

extern "C" void kernel_launch(void* const* d_in, const int* in_sizes, int n_in,
                              void* d_out, int out_size, void* d_ws, size_t ws_size,
                              hipStream_t stream) {
  const float* Q = (const float*)d_in[0];
  const float* K = (const float*)d_in[1];
  const float* V = (const float*)d_in[2];
  const float* S = (const float*)d_in[3];
  float* O = (float*)d_out;
  if (ws_size >= WS_NEEDED) {
    prepass<<<dim3(NT, B_N * NH), 256, 0, stream>>>(K, V, (char*)d_ws);
    fattn_main<<<dim3((SEQ / QT) * B_N * NH), 256, 0, stream>>>(Q, S, (const char*)d_ws, O);
  } else {
    fattn_fb<<<dim3(SEQ / 128, B_N * NH), 256, 0, stream>>>(Q, K, V, S, O);
  }
}

// Round 14
// 129.238 us; speedup vs baseline: 1.0112x; 1.0043x over previous
//
#include <hip/hip_runtime.h>
#include <hip/hip_bf16.h>

typedef __attribute__((ext_vector_type(8))) short short8;
typedef __attribute__((ext_vector_type(16))) float f32x16;

#define B_N 4
#define SEQ 2048
#define NH 16
#define HDIM 128
#define QT 128      // q rows per block (4 waves x 32) -> 2 async blocks/CU
#define QW 32       // q rows per wave
#define KT 64       // k tile
#define NT (SEQ / KT)            // 32 tiles
#define TILE_BYTES 32768         // 16KB K frags + 16KB V frags
#define WS_NEEDED ((size_t)B_N * NH * NT * TILE_BYTES)   // 67,108,864 B

static __device__ __forceinline__ unsigned short f2bf(float f) {
  union { __hip_bfloat16 h; unsigned short u; } cv;
  cv.h = __float2bfloat16(f);
  return cv.u;
}
static __device__ __forceinline__ unsigned int pack2(float a, float b) {
  return (unsigned int)f2bf(a) | ((unsigned int)f2bf(b) << 16);
}
static __device__ __forceinline__ unsigned int cvtpk(float lo, float hi) {
  unsigned int r;
  asm("v_cvt_pk_bf16_f32 %0, %1, %2" : "=v"(r) : "v"(lo), "v"(hi));
  return r;
}
// raw v_exp_f32 (log2-domain exp); OCML exp2f adds range-fixup VALU we don't need.
static __device__ __forceinline__ float rexp2(float x) {
  return __builtin_amdgcn_exp2f(x);
}
static __device__ __forceinline__ void gload16(const void* g, void* l) {
  __builtin_amdgcn_global_load_lds(
      (const __attribute__((address_space(1))) unsigned int*)g,
      (__attribute__((address_space(3))) unsigned int*)l, 16, 0, 0);
}

// ============ pre-pass: K,V fp32 -> bf16 fragment-major tiles in ws ============
// Tile image (32 KB): [16 K-frags][16 V-frags], each frag 1 KB = 64 lanes x 16B.
__global__ __launch_bounds__(256)
void prepass(const float* __restrict__ Kg, const float* __restrict__ Vg,
             char* __restrict__ ws)
{
  __shared__ __align__(16) char tile[16384];
  const int t  = blockIdx.x;        // 0..NT-1
  const int bh = blockIdx.y;        // 0..63
  const int b  = bh >> 4, hh = bh & (NH - 1);
  const int tid = threadIdx.x;
  const long strideS = (long)NH * HDIM;
  const float* kb = Kg + ((long)b * SEQ + t * KT) * strideS + (long)hh * HDIM;
  const float* vb = Vg + ((long)b * SEQ + t * KT) * strideS + (long)hh * HDIM;
  char* out = ws + ((long)bh * NT + t) * TILE_BYTES;

  // ---- K half ----
#pragma unroll
  for (int i = 0; i < 8; ++i) {
    int f4 = tid + i * 256;            // 0..2047
    int row = f4 >> 5, c4 = f4 & 31;   // row 0..63, float4-col 0..31
    float4 x = *(const float4*)(kb + (long)row * strideS + c4 * 4);
    uint2 w; w.x = pack2(x.x, x.y); w.y = pack2(x.z, x.w);
    int f    = (row >> 5) * 8 + (c4 >> 2);
    int lane = (((c4 >> 1) & 1) << 5) | (row & 31);
    *(uint2*)(tile + f * 1024 + lane * 16 + (c4 & 1) * 8) = w;
  }
  __syncthreads();
#pragma unroll
  for (int i = 0; i < 4; ++i)
    *(uint4*)(out + tid * 16 + i * 4096) = *(const uint4*)(tile + tid * 16 + i * 4096);
  __syncthreads();

  // ---- V half (transpose via 4x4 blocks) ----
#pragma unroll
  for (int i = 0; i < 2; ++i) {
    int blk = tid + i * 256;           // 0..511
    int d4 = blk & 31, k4 = blk >> 5;  // d-block 0..31, k-block 0..15
    const float* vp = vb + (long)(k4 * 4) * strideS + d4 * 4;
    float4 r0 = *(const float4*)vp;
    float4 r1 = *(const float4*)(vp + strideS);
    float4 r2 = *(const float4*)(vp + 2 * strideS);
    float4 r3 = *(const float4*)(vp + 3 * strideS);
    const float c0[4] = {r0.x, r0.y, r0.z, r0.w};
    const float c1[4] = {r1.x, r1.y, r1.z, r1.w};
    const float c2[4] = {r2.x, r2.y, r2.z, r2.w};
    const float c3[4] = {r3.x, r3.y, r3.z, r3.w};
    int g    = (d4 >> 3) * 4 + (k4 >> 2);
    int lhl  = ((k4 >> 1) & 1) << 5;
#pragma unroll
    for (int dd = 0; dd < 4; ++dd) {
      int lane = lhl | ((d4 & 7) * 4 + dd);
      uint2 w; w.x = pack2(c0[dd], c1[dd]); w.y = pack2(c2[dd], c3[dd]);
      *(uint2*)(tile + g * 1024 + lane * 16 + (k4 & 1) * 8) = w;
    }
  }
  __syncthreads();
#pragma unroll
  for (int i = 0; i < 4; ++i)
    *(uint4*)(out + 16384 + tid * 16 + i * 4096) =
        *(const uint4*)(tile + tid * 16 + i * 4096);
}

// ============ main kernel: round-12 core + counted vmcnt(4) barrier ============
__global__ __launch_bounds__(256, 2)
void fattn_main(const float* __restrict__ Qg, const float* __restrict__ Sg,
                const char* __restrict__ ws, float* __restrict__ Og)
{
  __shared__ __align__(16) char Kb[2][16384];   // K dbuf (gload_lds)
  __shared__ __align__(16) char Vb[3][16384];   // V triple buffer (gload_lds)

  const int tid  = threadIdx.x;
  const int wv   = tid >> 6;          // 0..3
  const int lane = tid & 63;
  const int l31  = lane & 31;
  const int h    = lane >> 5;

  // XCD/bh-grouped LPT: xcd = gi&7; deep blocks (bx=15) dispatched first.
  const int gi  = blockIdx.x;         // 0..1023
  const int xcd = gi & 7;
  const int j   = gi >> 3;            // 0..127
  const int bh  = xcd * 8 + (j & 7);
  const int bx  = 15 - (j >> 3);      // 0..15
  const int b   = bh >> 4;
  const int hh  = bh & (NH - 1);
  const int q0  = bx * QT;

  const float log2e = 1.4426950408889634f;
  const float slope = Sg[hh] * log2e;               // log2-domain ALiBi slope
  const float scale = 0.08838834764831845f * log2e; // (1/sqrt(128))*log2e
  const long strideS = (long)NH * HDIM;

  // Q fragments: B-operand (col = l31 = q, k = c*16 + h*8 + j), pre-scaled
  const int q0w  = q0 + wv * QW;
  const int qrow = q0w + l31;
  const float* qp = Qg + ((long)b * SEQ + qrow) * strideS + (long)hh * HDIM;
  short8 qf[8];
#pragma unroll
  for (int c = 0; c < 8; ++c) {
    const float* p = qp + c * 16 + h * 8;
    float4 x = *(const float4*)p;
    float4 y = *(const float4*)(p + 4);
    short8 f;
    f[0]=(short)f2bf(x.x*scale); f[1]=(short)f2bf(x.y*scale);
    f[2]=(short)f2bf(x.z*scale); f[3]=(short)f2bf(x.w*scale);
    f[4]=(short)f2bf(y.x*scale); f[5]=(short)f2bf(y.y*scale);
    f[6]=(short)f2bf(y.z*scale); f[7]=(short)f2bf(y.w*scale);
    qf[c] = f;
  }

  const float q_f  = (float)qrow;
  const float qb   = slope * q_f;
  const float h4   = (float)(4 * h);
  const float s32  = slope * 32.f;

  // ones fragment (bf16 1.0) for row-sum MFMA
  short8 ones;
#pragma unroll
  for (int i = 0; i < 8; ++i) ones[i] = (short)0x3F80;

  f32x16 acc[4], lacc;
#pragma unroll
  for (int nb = 0; nb < 4; ++nb)
#pragma unroll
    for (int i = 0; i < 16; ++i) acc[nb][i] = 0.f;
#pragma unroll
  for (int i = 0; i < 16; ++i) lacc[i] = 0.f;

  const int myend = (q0w + QW - 1) / KT;
  const int ntile = q0 / KT + 2;      // 2*bx + 2

  const char* wsbh = ws + (long)bh * NT * TILE_BYTES;

  // ---- prologue: tile 0 -> Kb[0], Vb[0] (4 waves x 4 segs each) ----
  {
    int seg = wv * 4;
#pragma unroll
    for (int sg = 0; sg < 4; ++sg) {
      gload16(wsbh + (seg + sg) * 1024 + lane * 16, &Kb[0][(seg + sg) * 1024]);
      gload16(wsbh + 16384 + (seg + sg) * 1024 + lane * 16, &Vb[0][(seg + sg) * 1024]);
    }
  }
  __syncthreads();

  short8 pa[4];          // P fragments of the PREVIOUS tile (pipeline state)
  int vcur = 0, vnx = 1; // V buffer rotation: tile t in buf t%3

  for (int t = 0; t < ntile; ++t) {
    // ---- stage tile t+1: K FIRST, then V (issue order matters for vmcnt) ----
    if (t + 1 < ntile) {
      const char* src = wsbh + (long)(t + 1) * TILE_BYTES;
      char* kn = Kb[(t + 1) & 1];
      char* vn = Vb[0] + vnx * 16384;
      int seg = wv * 4;
#pragma unroll
      for (int sg = 0; sg < 4; ++sg)
        gload16(src + (seg + sg) * 1024 + lane * 16, kn + (seg + sg) * 1024);
#pragma unroll
      for (int sg = 0; sg < 4; ++sg)
        gload16(src + 16384 + (seg + sg) * 1024 + lane * 16, vn + (seg + sg) * 1024);
    }

    const int lb = lane * 16;
    const int k0 = t * KT;
    const int vprev = (vcur == 0) ? 2 : vcur - 1;   // (t-1)%3

    if (t == 0) {
      // ======== first tile: QK + softmax only (fills the pipeline) ========
      const char* Kc = Kb[0];
      const float base = __builtin_fmaf(slope, (float)k0 + h4, -qb);
      f32x16 s0, s1;
#pragma unroll
      for (int i = 0; i < 16; ++i) {
        float b0 = __builtin_fmaf(slope, (float)((i & 3) + 8 * (i >> 2)), base);
        s0[i] = b0; s1[i] = b0 + s32;
      }
      __builtin_amdgcn_s_setprio(1);
#pragma unroll
      for (int c = 0; c < 8; ++c) {
        short8 ka = *(const short8*)(Kc + c * 1024 + lb);
        short8 k2 = *(const short8*)(Kc + (8 + c) * 1024 + lb);
        s0 = __builtin_amdgcn_mfma_f32_32x32x16_bf16(ka, qf[c], s0, 0, 0, 0);
        s1 = __builtin_amdgcn_mfma_f32_32x32x16_bf16(k2, qf[c], s1, 0, 0, 0);
      }
      __builtin_amdgcn_s_setprio(0);
      const bool diag = (t == myend);
      const float kb0 = (float)(k0 + 4 * h) - q_f;
#pragma unroll
      for (int kc = 0; kc < 4; ++kc) {
        const int i0 = (kc & 1) * 8;
        float sv[8];
#pragma unroll
        for (int e = 0; e < 8; ++e)
          sv[e] = (kc < 2) ? s0[i0 + e] : s1[i0 + e];
        if (diag) {
          const float add32 = (kc >= 2) ? 32.f : 0.f;
#pragma unroll
          for (int e = 0; e < 8; ++e) {
            const int i = i0 + e;
            float d0 = kb0 + (float)((i & 3) + 8 * (i >> 2)) + add32;
            sv[e] = (d0 > 0.f) ? -3.0e38f : sv[e];
          }
        }
        float pc[8];
#pragma unroll
        for (int e = 0; e < 8; ++e) pc[e] = rexp2(sv[e]);
        unsigned int a0 = cvtpk(pc[0], pc[1]);
        unsigned int b0 = cvtpk(pc[4], pc[5]);
        unsigned int a1 = cvtpk(pc[2], pc[3]);
        unsigned int b1 = cvtpk(pc[6], pc[7]);
        asm volatile("v_permlane32_swap_b32 %0, %1" : "+v"(a0), "+v"(b0));
        asm volatile("v_permlane32_swap_b32 %0, %1" : "+v"(a1), "+v"(b1));
        union { unsigned int w[4]; short8 v; } u;
        u.w[0] = a0; u.w[1] = a1; u.w[2] = b0; u.w[3] = b1;
        pa[kc] = u.v;
      }
    } else if (t <= myend) {
      // ======== steady state: QK(t) -> PV(t-1) -> softmax(t) overwrites pa ====
      const char* Kc = Kb[t & 1];
      const char* Vp = Vb[0] + vprev * 16384;
      const float base = __builtin_fmaf(slope, (float)k0 + h4, -qb);
      f32x16 s0, s1;
#pragma unroll
      for (int i = 0; i < 16; ++i) {
        float b0 = __builtin_fmaf(slope, (float)((i & 3) + 8 * (i >> 2)), base);
        s0[i] = b0; s1[i] = b0 + s32;
      }
      __builtin_amdgcn_s_setprio(1);
#pragma unroll
      for (int c = 0; c < 8; ++c) {
        short8 ka = *(const short8*)(Kc + c * 1024 + lb);
        short8 k2 = *(const short8*)(Kc + (8 + c) * 1024 + lb);
        s0 = __builtin_amdgcn_mfma_f32_32x32x16_bf16(ka, qf[c], s0, 0, 0, 0);
        s1 = __builtin_amdgcn_mfma_f32_32x32x16_bf16(k2, qf[c], s1, 0, 0, 0);
      }
      // ---- PV(t-1) + lacc(t-1) (uses pa + V(t-1); independent of s0/s1) ----
#pragma unroll
      for (int kc = 0; kc < 4; ++kc)
        lacc = __builtin_amdgcn_mfma_f32_32x32x16_bf16(pa[kc], ones, lacc, 0, 0, 0);
#pragma unroll
      for (int nb = 0; nb < 4; ++nb)
#pragma unroll
        for (int kc = 0; kc < 4; ++kc) {
          short8 vf = *(const short8*)(Vp + (nb * 4 + kc) * 1024 + lb);
          acc[nb] = __builtin_amdgcn_mfma_f32_32x32x16_bf16(pa[kc], vf, acc[nb], 0, 0, 0);
        }
      __builtin_amdgcn_s_setprio(0);

      // ---- softmax(t): raw v_exp_f32, writes pa in place ----
      const bool diag = (t == myend);
      const float kb0 = (float)(k0 + 4 * h) - q_f;
#pragma unroll
      for (int kc = 0; kc < 4; ++kc) {
        const int i0 = (kc & 1) * 8;
        float sv[8];
#pragma unroll
        for (int e = 0; e < 8; ++e)
          sv[e] = (kc < 2) ? s0[i0 + e] : s1[i0 + e];
        if (diag) {
          const float add32 = (kc >= 2) ? 32.f : 0.f;
#pragma unroll
          for (int e = 0; e < 8; ++e) {
            const int i = i0 + e;
            float d0 = kb0 + (float)((i & 3) + 8 * (i >> 2)) + add32;
            sv[e] = (d0 > 0.f) ? -3.0e38f : sv[e];
          }
        }
        float pc[8];
#pragma unroll
        for (int e = 0; e < 8; ++e) pc[e] = rexp2(sv[e]);
        unsigned int a0 = cvtpk(pc[0], pc[1]);
        unsigned int b0 = cvtpk(pc[4], pc[5]);
        unsigned int a1 = cvtpk(pc[2], pc[3]);
        unsigned int b1 = cvtpk(pc[6], pc[7]);
        asm volatile("v_permlane32_swap_b32 %0, %1" : "+v"(a0), "+v"(b0));
        asm volatile("v_permlane32_swap_b32 %0, %1" : "+v"(a1), "+v"(b1));
        union { unsigned int w[4]; short8 v; } u;
        u.w[0] = a0; u.w[1] = a1; u.w[2] = b0; u.w[3] = b1;
        pa[kc] = u.v;
      }
    } else if (t == myend + 1) {
      // ======== drain: final PV of tile myend ========
      const char* Vp = Vb[0] + vprev * 16384;
      __builtin_amdgcn_s_setprio(1);
#pragma unroll
      for (int kc = 0; kc < 4; ++kc)
        lacc = __builtin_amdgcn_mfma_f32_32x32x16_bf16(pa[kc], ones, lacc, 0, 0, 0);
#pragma unroll
      for (int nb = 0; nb < 4; ++nb)
#pragma unroll
        for (int kc = 0; kc < 4; ++kc) {
          short8 vf = *(const short8*)(Vp + (nb * 4 + kc) * 1024 + lb);
          acc[nb] = __builtin_amdgcn_mfma_f32_32x32x16_bf16(pa[kc], vf, acc[nb], 0, 0, 0);
        }
      __builtin_amdgcn_s_setprio(0);
    }

    // ---- counted-vmcnt barrier (T4): drain only the K(t+1) loads; the 4
    // V(t+1) loads stay in flight (V has 2 iterations of slack — first read
    // at iter t+2). Each wave pre-drains its OWN older loads, then the
    // barrier makes that a cross-wave guarantee: after it, all waves' K(t+1)
    // and V(t) writes to LDS are complete.
    asm volatile("s_waitcnt vmcnt(4)" ::: "memory");
    __builtin_amdgcn_s_barrier();
    vcur = vnx; vnx = (vnx == 2) ? 0 : vnx + 1;
  }

  // full drain + barrier: the last V-tile's loads may still be in flight
  __syncthreads();

  // ---- post-loop drain for waves whose diagonal tile is the last staged ----
  if (myend == ntile - 1) {
    const int lb = lane * 16;
    const char* Vp = Vb[0] + ((ntile - 1) % 3) * 16384;
#pragma unroll
    for (int kc = 0; kc < 4; ++kc)
      lacc = __builtin_amdgcn_mfma_f32_32x32x16_bf16(pa[kc], ones, lacc, 0, 0, 0);
#pragma unroll
    for (int nb = 0; nb < 4; ++nb)
#pragma unroll
      for (int kc = 0; kc < 4; ++kc) {
        short8 vf = *(const short8*)(Vp + (nb * 4 + kc) * 1024 + lb);
        acc[nb] = __builtin_amdgcn_mfma_f32_32x32x16_bf16(pa[kc], vf, acc[nb], 0, 0, 0);
      }
  }

  // ---- epilogue: O / l ----
  float* op = Og + ((long)b * SEQ + q0w) * strideS + (long)hh * HDIM;
#pragma unroll
  for (int i = 0; i < 16; ++i) {
    int qr = (i & 3) + 8 * (i >> 2) + 4 * h;
    float iv = 1.0f / lacc[i];
    long rb = (long)qr * strideS;
#pragma unroll
    for (int nb = 0; nb < 4; ++nb)
      op[rb + nb * 32 + l31] = acc[nb][i] * iv;
  }
}

// ============ fallback (round-2 kernel, proven): used if ws too small ============
__global__ __launch_bounds__(256, 2)
void fattn_fb(const float* __restrict__ Qg, const float* __restrict__ Kg,
              const float* __restrict__ Vg, const float* __restrict__ Sg,
              float* __restrict__ Og)
{
  __shared__ __align__(16) char Ks[KT * HDIM * 2];
  __shared__ __align__(16) char Vs[HDIM * KT * 2];
  const int tid  = threadIdx.x;
  const int wv   = tid >> 6;
  const int lane = tid & 63;
  const int l31  = lane & 31;
  const int h    = lane >> 5;
  const int q0 = blockIdx.x * 128;
  const int bh = blockIdx.y;
  const int b  = bh >> 4;
  const int hh = bh & (NH - 1);
  const float slope = Sg[hh];
  const float scale = 0.08838834764831845f;
  const long strideS = (long)NH * HDIM;
  const int q0w  = q0 + wv * QW;
  const int qrow = q0w + l31;
  const float* qp = Qg + ((long)b * SEQ + qrow) * strideS + (long)hh * HDIM;
  short8 qf[8];
#pragma unroll
  for (int c = 0; c < 8; ++c) {
    const float* p = qp + c * 16 + h * 8;
    float4 x = *(const float4*)p;
    float4 y = *(const float4*)(p + 4);
    short8 f;
    f[0]=(short)f2bf(x.x*scale); f[1]=(short)f2bf(x.y*scale);
    f[2]=(short)f2bf(x.z*scale); f[3]=(short)f2bf(x.w*scale);
    f[4]=(short)f2bf(y.x*scale); f[5]=(short)f2bf(y.y*scale);
    f[6]=(short)f2bf(y.z*scale); f[7]=(short)f2bf(y.w*scale);
    qf[c] = f;
  }
  float m_run = -1e30f, l_run = 0.f;
  f32x16 acc[4];
#pragma unroll
  for (int nb = 0; nb < 4; ++nb)
#pragma unroll
    for (int i = 0; i < 16; ++i) acc[nb][i] = 0.f;
  const float* kb = Kg + (long)b * SEQ * strideS + (long)hh * HDIM;
  const float* vb = Vg + (long)b * SEQ * strideS + (long)hh * HDIM;
  const float q_f = (float)qrow;
  const int myend = (q0w + QW - 1) / KT;
  const int ntile = q0 / KT + 2;
  for (int t = 0; t < ntile; ++t) {
    const int k0 = t * KT;
    __syncthreads();
#pragma unroll
    for (int i = 0; i < 8; ++i) {
      int f4 = tid + i * 256;
      int row = f4 >> 5, c4 = f4 & 31;
      float4 x = *(const float4*)(kb + (long)(k0 + row) * strideS + c4 * 4);
      uint2 w; w.x = pack2(x.x, x.y); w.y = pack2(x.z, x.w);
      int byt = (row * 256 + c4 * 8) ^ ((row & 7) << 4);
      *(uint2*)(Ks + byt) = w;
    }
#pragma unroll
    for (int i = 0; i < 2; ++i) {
      int blk = tid + i * 256;
      int d4 = blk & 31, k4 = blk >> 5;
      const float* vp = vb + (long)(k0 + k4 * 4) * strideS + d4 * 4;
      float4 r0 = *(const float4*)vp;
      float4 r1 = *(const float4*)(vp + strideS);
      float4 r2 = *(const float4*)(vp + 2 * strideS);
      float4 r3 = *(const float4*)(vp + 3 * strideS);
      const float c0[4] = {r0.x, r0.y, r0.z, r0.w};
      const float c1[4] = {r1.x, r1.y, r1.z, r1.w};
      const float c2[4] = {r2.x, r2.y, r2.z, r2.w};
      const float c3[4] = {r3.x, r3.y, r3.z, r3.w};
#pragma unroll
      for (int dd = 0; dd < 4; ++dd) {
        int d = d4 * 4 + dd;
        uint2 w; w.x = pack2(c0[dd], c1[dd]); w.y = pack2(c2[dd], c3[dd]);
        int byt = (d * (KT * 2) + k4 * 8) ^ ((d & 7) << 4);
        *(uint2*)(Vs + byt) = w;
      }
    }
    __syncthreads();
    if (t <= myend) {
      f32x16 s0, s1;
#pragma unroll
      for (int i = 0; i < 16; ++i) { s0[i] = 0.f; s1[i] = 0.f; }
      const int swzk = (l31 & 7) << 4;
#pragma unroll
      for (int c = 0; c < 8; ++c) {
        int colb = c * 32 + h * 16;
        short8 ka = *(const short8*)(Ks + ((l31 * 256 + colb) ^ swzk));
        short8 kbf = *(const short8*)(Ks + (((l31 + 32) * 256 + colb) ^ swzk));
        s0 = __builtin_amdgcn_mfma_f32_32x32x16_bf16(ka, qf[c], s0, 0, 0, 0);
        s1 = __builtin_amdgcn_mfma_f32_32x32x16_bf16(kbf, qf[c], s1, 0, 0, 0);
      }
      float p[32];
      float pm = -1e30f;
#pragma unroll
      for (int i = 0; i < 16; ++i) {
        float kp0 = (float)(k0 + (i & 3) + 8 * (i >> 2) + 4 * h);
        float d0 = kp0 - q_f;
        float v0 = s0[i] + slope * d0;
        v0 = (d0 > 0.f) ? -1e30f : v0;
        p[i] = v0;
        float d1 = d0 + 32.f;
        float v1 = s1[i] + slope * d1;
        v1 = (d1 > 0.f) ? -1e30f : v1;
        p[16 + i] = v1;
        pm = fmaxf(pm, fmaxf(v0, v1));
      }
      pm = fmaxf(pm, __shfl_xor(pm, 32));
      if (!__all(pm <= m_run)) {
        float M = fmaxf(m_run, pm);
        float alpha = __expf(m_run - M);
        m_run = M;
#pragma unroll
        for (int i = 0; i < 16; ++i) {
          int qr = (i & 3) + 8 * (i >> 2) + 4 * h;
          float al = __shfl(alpha, qr, 64);
          acc[0][i] *= al; acc[1][i] *= al; acc[2][i] *= al; acc[3][i] *= al;
        }
        l_run *= alpha;
      }
      float ps = 0.f;
#pragma unroll
      for (int i = 0; i < 32; ++i) {
        float e = __expf(p[i] - m_run);
        p[i] = e;
        ps += e;
      }
      ps += __shfl_xor(ps, 32);
      l_run += ps;
      short8 pa[4];
#pragma unroll
      for (int kc = 0; kc < 4; ++kc) {
        const int base = kc * 8;
        unsigned int a0 = cvtpk(p[base + 0], p[base + 1]);
        unsigned int b0 = cvtpk(p[base + 4], p[base + 5]);
        unsigned int a1 = cvtpk(p[base + 2], p[base + 3]);
        unsigned int b1 = cvtpk(p[base + 6], p[base + 7]);
        asm volatile("v_permlane32_swap_b32 %0, %1" : "+v"(a0), "+v"(b0));
        asm volatile("v_permlane32_swap_b32 %0, %1" : "+v"(a1), "+v"(b1));
        union { unsigned int w[4]; short8 v; } u;
        u.w[0] = a0; u.w[1] = a1; u.w[2] = b0; u.w[3] = b1;
        pa[kc] = u.v;
      }
#pragma unroll
      for (int nb = 0; nb < 4; ++nb) {
        int rowb = (nb * 32 + l31) * (KT * 2);
        int sw = ((nb * 32 + l31) & 7) << 4;
#pragma unroll
        for (int kc = 0; kc < 4; ++kc) {
          short8 vf = *(const short8*)(Vs + ((rowb + kc * 32 + h * 16) ^ sw));
          acc[nb] = __builtin_amdgcn_mfma_f32_32x32x16_bf16(pa[kc], vf, acc[nb], 0, 0, 0);
        }
      }
    }
  }
  float inv = 1.0f / l_run;
  float* op = Og + ((long)b * SEQ + q0w) * strideS + (long)hh * HDIM;
#pragma unroll
  for (int i = 0; i < 16; ++i) {
    int qr = (i & 3) + 8 * (i >> 2) + 4 * h;
    float iv = __shfl(inv, qr, 64);
    long rb = (long)qr * strideS;
#pragma unroll
    for (int nb = 0; nb < 4; ++nb)
      op[rb + nb * 32 + l31] = acc[nb][i] * iv;
  }
}

extern "C" void kernel_launch(void* const* d_in, const int* in_sizes, int n_in,
                              void* d_out, int out_size, void* d_ws, size_t ws_size,
                              hipStream_t stream) {
  const float* Q = (const float*)d_in[0];
  const float* K = (const float*)d_in[1];
  const float* V = (const float*)d_in[2];
  const float* S = (const float*)d_in[3];
  float* O = (float*)d_out;
  if (ws_size >= WS_NEEDED) {
    prepass<<<dim3(NT, B_N * NH), 256, 0, stream>>>(K, V, (char*)d_ws);
    fattn_main<<<dim3((SEQ / QT) * B_N * NH), 256, 0, stream>>>(Q, S, (const char*)d_ws, O);
  } else {
    fattn_fb<<<dim3(SEQ / 128, B_N * NH), 256, 0, stream>>>(Q, K, V, S, O);
  }
}